// Round 4
// baseline (83.075 us; speedup 1.0000x reference)
//
#include <hip/hip_runtime.h>

// Problem constants (match reference)
#define NXG 2048
#define NYG 2048
// hx = hy = 1/2048 -> 1/h = 2048, 1/(2h) = 1024
__device__ __forceinline__ float inv_h()  { return 2048.0f; }
__device__ __forceinline__ float inv_2h() { return 1024.0f; }

#define BLOCK 256
#define GRID  1024   // 1024 x 256 = 262,144 threads = one 4-row x float4 chunk each

// Single kernel: each thread handles a 4-row strip x 4-col chunk:
//   strip s -> rows 4s..4s+3, cols j4..j4+3.
// x-stencil needs rows 4s-1..4s+4 -> 6 float4 loads per 16 outputs
// (1.5 streams/row vs 2 for row-pairs, 3 for naive). Clamped boundary rows
// collapse to already-loaded rows (Rm==R0 at s=0, Rp==R3 at s=511) with the
// one-sided 1/h scale. Block result lands in out[0] via one float atomicAdd
// per block (out zeroed by a memset node in kernel_launch).
// Block->data swizzle gives each XCD a contiguous 256-row band so shared
// boundary rows are L2-deduplicated within an XCD.
__global__ __launch_bounds__(BLOCK) void
energy_kernel(const float* __restrict__ phi, float* __restrict__ out) {
    // XCD-band swizzle: b' = (b & 7) * 128 + (b >> 3)
    const int bs = ((blockIdx.x & 7) << 7) + (blockIdx.x >> 3);
    const int c  = bs * BLOCK + threadIdx.x;   // 0..262143
    const int s  = c >> 9;                     // strip 0..511
    const int j4 = (c & 511) << 2;             // col start 0..2044

    const int i0 = 4 * s;
    const int rm = (s > 0)   ? i0 - 1 : 0;
    const int rp = (s < 511) ? i0 + 4 : NXG - 1;
    const float sx0 = (s == 0)   ? inv_h() : inv_2h();
    const float sx3 = (s == 511) ? inv_h() : inv_2h();

    const float* Rm = phi + (size_t)rm * NYG;
    const float* R0 = phi + (size_t)(i0 + 0) * NYG;
    const float* R1 = phi + (size_t)(i0 + 1) * NYG;
    const float* R2 = phi + (size_t)(i0 + 2) * NYG;
    const float* R3 = phi + (size_t)(i0 + 3) * NYG;
    const float* Rp = phi + (size_t)rp * NYG;

    const float4 m  = *(const float4*)(Rm + j4);
    const float4 r0 = *(const float4*)(R0 + j4);
    const float4 r1 = *(const float4*)(R1 + j4);
    const float4 r2 = *(const float4*)(R2 + j4);
    const float4 r3 = *(const float4*)(R3 + j4);
    const float4 p  = *(const float4*)(Rp + j4);

    float acc = 0.0f;

    // x-direction: vx(i0)=(R1-Rm)*sx0, vx(i1)=(R2-R0)/2h, vx(i2)=(R3-R1)/2h,
    // vx(i3)=(Rp-R2)*sx3. Signs irrelevant (squared).
    {
        float v;
        v = (r1.x - m.x) * sx0; acc += v * v;
        v = (r1.y - m.y) * sx0; acc += v * v;
        v = (r1.z - m.z) * sx0; acc += v * v;
        v = (r1.w - m.w) * sx0; acc += v * v;
        v = (r2.x - r0.x) * inv_2h(); acc += v * v;
        v = (r2.y - r0.y) * inv_2h(); acc += v * v;
        v = (r2.z - r0.z) * inv_2h(); acc += v * v;
        v = (r2.w - r0.w) * inv_2h(); acc += v * v;
        v = (r3.x - r1.x) * inv_2h(); acc += v * v;
        v = (r3.y - r1.y) * inv_2h(); acc += v * v;
        v = (r3.z - r1.z) * inv_2h(); acc += v * v;
        v = (r3.w - r1.w) * inv_2h(); acc += v * v;
        v = (p.x - r2.x) * sx3; acc += v * v;
        v = (p.y - r2.y) * sx3; acc += v * v;
        v = (p.z - r2.z) * sx3; acc += v * v;
        v = (p.w - r2.w) * sx3; acc += v * v;
    }

    // y-direction for rows R0..R3: interior central diffs from the float4,
    // edge elements need one scalar (same cache lines as neighbors' float4s).
    {
        float l0, l1, l2, l3, q0, q1, q2, q3;
        float e0, e3;  // scales for first/last element of the chunk
        if (j4 == 0) {
            l0 = r0.x; l1 = r1.x; l2 = r2.x; l3 = r3.x; e0 = inv_h();
        } else {
            l0 = R0[j4 - 1]; l1 = R1[j4 - 1]; l2 = R2[j4 - 1]; l3 = R3[j4 - 1];
            e0 = inv_2h();
        }
        if (j4 + 4 == NYG) {
            q0 = r0.w; q1 = r1.w; q2 = r2.w; q3 = r3.w; e3 = inv_h();
        } else {
            q0 = R0[j4 + 4]; q1 = R1[j4 + 4]; q2 = R2[j4 + 4]; q3 = R3[j4 + 4];
            e3 = inv_2h();
        }
        float v;
        v = (r0.y - l0) * e0; acc += v * v;
        v = (r1.y - l1) * e0; acc += v * v;
        v = (r2.y - l2) * e0; acc += v * v;
        v = (r3.y - l3) * e0; acc += v * v;
        v = (r0.z - r0.x) * inv_2h(); acc += v * v;
        v = (r1.z - r1.x) * inv_2h(); acc += v * v;
        v = (r2.z - r2.x) * inv_2h(); acc += v * v;
        v = (r3.z - r3.x) * inv_2h(); acc += v * v;
        v = (r0.w - r0.y) * inv_2h(); acc += v * v;
        v = (r1.w - r1.y) * inv_2h(); acc += v * v;
        v = (r2.w - r2.y) * inv_2h(); acc += v * v;
        v = (r3.w - r3.y) * inv_2h(); acc += v * v;
        v = (q0 - r0.z) * e3; acc += v * v;
        v = (q1 - r1.z) * e3; acc += v * v;
        v = (q2 - r2.z) * e3; acc += v * v;
        v = (q3 - r3.z) * e3; acc += v * v;
    }

    // wave (64-lane) shuffle reduction
    #pragma unroll
    for (int off = 32; off > 0; off >>= 1)
        acc += __shfl_down(acc, off, 64);

    __shared__ float smem[BLOCK / 64];
    const int lane = threadIdx.x & 63;
    const int wave = threadIdx.x >> 6;
    if (lane == 0) smem[wave] = acc;
    __syncthreads();
    if (threadIdx.x == 0) {
        float s4 = 0.0f;
        #pragma unroll
        for (int w = 0; w < BLOCK / 64; ++w) s4 += smem[w];
        atomicAdd(out, 0.5f * s4);   // device-scope fp32 atomic, 1024 total
    }
}

extern "C" void kernel_launch(void* const* d_in, const int* in_sizes, int n_in,
                              void* d_out, int out_size, void* d_ws, size_t ws_size,
                              hipStream_t stream) {
    // d_in[0] = pos (unused by the reference), d_in[1] = potential_field [2048*2048] f32
    const float* phi = (const float*)d_in[1];
    float* out = (float*)d_out;

    // d_out is poisoned to 0xAA before every timed replay — zero it ourselves.
    hipMemsetAsync(out, 0, sizeof(float) * (size_t)out_size, stream);
    energy_kernel<<<GRID, BLOCK, 0, stream>>>(phi, out);
}

// Round 5
// 73.646 us; speedup vs baseline: 1.1280x; 1.1280x over previous
//
#include <hip/hip_runtime.h>

// Problem constants (match reference)
#define NXG 2048
#define NYG 2048
// hx = hy = 1/2048 -> 1/h = 2048, 1/(2h) = 1024
__device__ __forceinline__ float inv_h()  { return 2048.0f; }
__device__ __forceinline__ float inv_2h() { return 1024.0f; }

#define BLOCK 256
#define GRID  1024   // 1024 x 256 threads = 262,144 = one 4-row x float4 chunk each

// Kernel 1: each thread handles a 4-row strip x 4-col chunk:
//   strip s -> rows 4s..4s+3, cols j4..j4+3.
// x-stencil needs rows 4s-1..4s+4 -> 6 float4 loads per 16 outputs
// (1.5 streams/row vs 2 for row-pairs, 3 for naive). Clamped boundary rows
// collapse to already-loaded rows (Rm==R0 at s=0, Rp==R3 at s=511) with the
// one-sided 1/h scale. Natural block order (no swizzle — R4 showed the
// swizzle+atomic bundle regressed). Block partials -> d_ws, reduced by kernel 2.
__global__ __launch_bounds__(BLOCK) void
energy_partial_kernel(const float* __restrict__ phi, float* __restrict__ partial) {
    const int c  = blockIdx.x * BLOCK + threadIdx.x;   // 0..262143
    const int s  = c >> 9;                             // strip 0..511
    const int j4 = (c & 511) << 2;                     // col start 0..2044

    const int i0 = 4 * s;
    const int rm = (s > 0)   ? i0 - 1 : 0;
    const int rp = (s < 511) ? i0 + 4 : NXG - 1;
    const float sx0 = (s == 0)   ? inv_h() : inv_2h();
    const float sx3 = (s == 511) ? inv_h() : inv_2h();

    const float* Rm = phi + (size_t)rm * NYG;
    const float* R0 = phi + (size_t)(i0 + 0) * NYG;
    const float* R1 = phi + (size_t)(i0 + 1) * NYG;
    const float* R2 = phi + (size_t)(i0 + 2) * NYG;
    const float* R3 = phi + (size_t)(i0 + 3) * NYG;
    const float* Rp = phi + (size_t)rp * NYG;

    const float4 m  = *(const float4*)(Rm + j4);
    const float4 r0 = *(const float4*)(R0 + j4);
    const float4 r1 = *(const float4*)(R1 + j4);
    const float4 r2 = *(const float4*)(R2 + j4);
    const float4 r3 = *(const float4*)(R3 + j4);
    const float4 p  = *(const float4*)(Rp + j4);

    float acc = 0.0f;

    // x-direction: vx(i0)=(R1-Rm)*sx0, vx(i1)=(R2-R0)/2h, vx(i2)=(R3-R1)/2h,
    // vx(i3)=(Rp-R2)*sx3. Signs irrelevant (squared).
    {
        float v;
        v = (r1.x - m.x) * sx0; acc += v * v;
        v = (r1.y - m.y) * sx0; acc += v * v;
        v = (r1.z - m.z) * sx0; acc += v * v;
        v = (r1.w - m.w) * sx0; acc += v * v;
        v = (r2.x - r0.x) * inv_2h(); acc += v * v;
        v = (r2.y - r0.y) * inv_2h(); acc += v * v;
        v = (r2.z - r0.z) * inv_2h(); acc += v * v;
        v = (r2.w - r0.w) * inv_2h(); acc += v * v;
        v = (r3.x - r1.x) * inv_2h(); acc += v * v;
        v = (r3.y - r1.y) * inv_2h(); acc += v * v;
        v = (r3.z - r1.z) * inv_2h(); acc += v * v;
        v = (r3.w - r1.w) * inv_2h(); acc += v * v;
        v = (p.x - r2.x) * sx3; acc += v * v;
        v = (p.y - r2.y) * sx3; acc += v * v;
        v = (p.z - r2.z) * sx3; acc += v * v;
        v = (p.w - r2.w) * sx3; acc += v * v;
    }

    // y-direction for rows R0..R3: interior central diffs from the float4,
    // edge elements need one scalar (same cache lines as neighbors' float4s).
    {
        float l0, l1, l2, l3, q0, q1, q2, q3;
        float e0, e3;  // scales for first/last element of the chunk
        if (j4 == 0) {
            l0 = r0.x; l1 = r1.x; l2 = r2.x; l3 = r3.x; e0 = inv_h();
        } else {
            l0 = R0[j4 - 1]; l1 = R1[j4 - 1]; l2 = R2[j4 - 1]; l3 = R3[j4 - 1];
            e0 = inv_2h();
        }
        if (j4 + 4 == NYG) {
            q0 = r0.w; q1 = r1.w; q2 = r2.w; q3 = r3.w; e3 = inv_h();
        } else {
            q0 = R0[j4 + 4]; q1 = R1[j4 + 4]; q2 = R2[j4 + 4]; q3 = R3[j4 + 4];
            e3 = inv_2h();
        }
        float v;
        v = (r0.y - l0) * e0; acc += v * v;
        v = (r1.y - l1) * e0; acc += v * v;
        v = (r2.y - l2) * e0; acc += v * v;
        v = (r3.y - l3) * e0; acc += v * v;
        v = (r0.z - r0.x) * inv_2h(); acc += v * v;
        v = (r1.z - r1.x) * inv_2h(); acc += v * v;
        v = (r2.z - r2.x) * inv_2h(); acc += v * v;
        v = (r3.z - r3.x) * inv_2h(); acc += v * v;
        v = (r0.w - r0.y) * inv_2h(); acc += v * v;
        v = (r1.w - r1.y) * inv_2h(); acc += v * v;
        v = (r2.w - r2.y) * inv_2h(); acc += v * v;
        v = (r3.w - r3.y) * inv_2h(); acc += v * v;
        v = (q0 - r0.z) * e3; acc += v * v;
        v = (q1 - r1.z) * e3; acc += v * v;
        v = (q2 - r2.z) * e3; acc += v * v;
        v = (q3 - r3.z) * e3; acc += v * v;
    }

    // wave (64-lane) shuffle reduction
    #pragma unroll
    for (int off = 32; off > 0; off >>= 1)
        acc += __shfl_down(acc, off, 64);

    __shared__ float smem[BLOCK / 64];
    const int lane = threadIdx.x & 63;
    const int wave = threadIdx.x >> 6;
    if (lane == 0) smem[wave] = acc;
    __syncthreads();
    if (threadIdx.x == 0) {
        float s4 = 0.0f;
        #pragma unroll
        for (int w = 0; w < BLOCK / 64; ++w) s4 += smem[w];
        partial[blockIdx.x] = s4;
    }
}

// Kernel 2: single block reduces GRID partials, writes 0.5 * sum.
__global__ __launch_bounds__(BLOCK) void
energy_finalize_kernel(const float* __restrict__ partial, float* __restrict__ out) {
    float acc = 0.0f;
    for (int idx = threadIdx.x; idx < GRID; idx += BLOCK)
        acc += partial[idx];

    #pragma unroll
    for (int off = 32; off > 0; off >>= 1)
        acc += __shfl_down(acc, off, 64);

    __shared__ float smem[BLOCK / 64];
    const int lane = threadIdx.x & 63;
    const int wave = threadIdx.x >> 6;
    if (lane == 0) smem[wave] = acc;
    __syncthreads();
    if (threadIdx.x == 0) {
        float s = 0.0f;
        #pragma unroll
        for (int w = 0; w < BLOCK / 64; ++w) s += smem[w];
        out[0] = 0.5f * s;
    }
}

extern "C" void kernel_launch(void* const* d_in, const int* in_sizes, int n_in,
                              void* d_out, int out_size, void* d_ws, size_t ws_size,
                              hipStream_t stream) {
    // d_in[0] = pos (unused by the reference), d_in[1] = potential_field [2048*2048] f32
    const float* phi = (const float*)d_in[1];
    float* out = (float*)d_out;
    float* partial = (float*)d_ws;  // GRID floats of scratch

    energy_partial_kernel<<<GRID, BLOCK, 0, stream>>>(phi, partial);
    energy_finalize_kernel<<<1, BLOCK, 0, stream>>>(partial, out);
}